// Round 1
// baseline (496.309 us; speedup 1.0000x reference)
//
#include <hip/hip_runtime.h>

#define MSEQ 2048

// ---------------- Projection GEMM ----------------
// [Q|K|V] = x @ [Wq|Wk|Wv] + bias.  x:(8192,512) fp32 row-major.
// Q,K:(8192,128), V:(8192,512) fp32 row-major in workspace.
__global__ __launch_bounds__(256, 4) void proj_kernel(
    const float* __restrict__ x,
    const float* __restrict__ Wq, const float* __restrict__ bq,
    const float* __restrict__ Wk, const float* __restrict__ bk,
    const float* __restrict__ Wv, const float* __restrict__ bv,
    float* __restrict__ Q, float* __restrict__ K, float* __restrict__ V)
{
    const int nt = blockIdx.x;         // 0..11: column tile of 64 across [q|k|v]
    const int r0 = blockIdx.y * 64;    // row tile

    const float* W; const float* bias; float* out; int ld; int n0;
    if (nt < 2)      { W = Wq; bias = bq; out = Q; ld = 128; n0 = nt * 64; }
    else if (nt < 4) { W = Wk; bias = bk; out = K; ld = 128; n0 = (nt - 2) * 64; }
    else             { W = Wv; bias = bv; out = V; ld = 512; n0 = (nt - 4) * 64; }

    __shared__ float As[16][72];   // As[k][m] (x tile transposed); stride 72 -> 288B rows, 16B aligned
    __shared__ float Bs[16][72];   // Bs[k][n]

    const int t  = threadIdx.x;
    const int tx = t & 15;         // n-subtile
    const int ty = t >> 4;         // m-subtile

    float acc[4][4] = {};

    for (int kk = 0; kk < 512; kk += 16) {
        // stage A tile (64 rows x 16 k), transposed into LDS
        {
            const int row = t >> 2, ch = t & 3;
            const float4 a4 = *(const float4*)(x + (r0 + row) * 512 + kk + ch * 4);
            As[ch*4+0][row] = a4.x; As[ch*4+1][row] = a4.y;
            As[ch*4+2][row] = a4.z; As[ch*4+3][row] = a4.w;
        }
        // stage B tile (16 k x 64 n)
        {
            const int krow = t >> 4, ch = t & 15;
            const float4 b4 = *(const float4*)(W + (kk + krow) * ld + n0 + ch * 4);
            *(float4*)&Bs[krow][ch*4] = b4;
        }
        __syncthreads();
        #pragma unroll
        for (int k = 0; k < 16; ++k) {
            const float4 a4 = *(const float4*)&As[k][ty*4];
            const float4 b4 = *(const float4*)&Bs[k][tx*4];
            const float a[4]  = {a4.x, a4.y, a4.z, a4.w};
            const float bb[4] = {b4.x, b4.y, b4.z, b4.w};
            #pragma unroll
            for (int i = 0; i < 4; ++i)
                #pragma unroll
                for (int j = 0; j < 4; ++j)
                    acc[i][j] = fmaf(a[i], bb[j], acc[i][j]);
        }
        __syncthreads();
    }

    const float4 b4 = *(const float4*)(bias + n0 + tx*4);
    const float bb[4] = {b4.x, b4.y, b4.z, b4.w};
    #pragma unroll
    for (int i = 0; i < 4; ++i) {
        float4 o;
        o.x = acc[i][0] + bb[0]; o.y = acc[i][1] + bb[1];
        o.z = acc[i][2] + bb[2]; o.w = acc[i][3] + bb[3];
        *(float4*)(out + (r0 + ty*4 + i) * ld + n0 + tx*4) = o;
    }
}

// ---------------- Fused masked attention ----------------
// Per (b,h, 64-query tile): stream over 64-key tiles.
// w = mask_n * exp(relu(q.k/4)); O = (sum w*v) / (sum w) * gamma.
// (softmax denom cancels against mask renorm; relu>=0 -> exp in [1,~7], no max needed)
__global__ __launch_bounds__(256, 4) void attn_kernel(
    const float* __restrict__ Q, const float* __restrict__ K,
    const float* __restrict__ V, const int* __restrict__ mask,
    const float* __restrict__ gamma, float* __restrict__ out)
{
    const int bh = blockIdx.x;        // 0..31
    const int b  = bh >> 3, h = bh & 7;
    const int m0 = blockIdx.y * 64;
    const int t  = threadIdx.x;

    __shared__ float kT[16][72];      // kT[d][kn], stride 72 (288B, aligned, 2-way max)
    __shared__ float vt[64][72];      // vt[kn][c]
    __shared__ float wt[64][68];      // wt[qr][kn], stride 68 (272B = 17*16B aligned, breaks 4-row bank alias)
    __shared__ float msk[64];
    __shared__ float wsums[64];
    float (*qs)[16] = (float (*)[16])&wt[0][0];  // q staging overlays wt (disjoint lifetimes)

    const int qr = t >> 2;   // score phase: query row 0..63
    const int cg = t & 3;    // score phase: 16-key column group
    const int rg = t >> 4;   // accum phase: 4-row group 0..15
    const int c4 = t & 15;   // accum phase: 4-col group 0..15

    // stage Q tile (64 x 16)
    {
        const int row = t >> 2, ch = t & 3;
        const float4 q4 = *(const float4*)(Q + (b*MSEQ + m0 + row)*128 + h*16 + ch*4);
        *(float4*)&qs[row][ch*4] = q4;
    }
    if (t < 64) wsums[t] = 0.f;
    __syncthreads();

    float qreg[16];
    #pragma unroll
    for (int u = 0; u < 4; ++u)
        *(float4*)&qreg[u*4] = *(const float4*)&qs[qr][u*4];

    float acc[4][4] = {};

    for (int kt = 0; kt < 32; ++kt) {
        const int kn0 = kt * 64;
        // ---- stage K^T (16x64), V (64x64), mask ----
        {
            const int row = t >> 2, ch = t & 3;
            const float4 k4 = *(const float4*)(K + (b*MSEQ + kn0 + row)*128 + h*16 + ch*4);
            kT[ch*4+0][row] = k4.x; kT[ch*4+1][row] = k4.y;
            kT[ch*4+2][row] = k4.z; kT[ch*4+3][row] = k4.w;
        }
        #pragma unroll
        for (int i = 0; i < 4; ++i) {
            const int idx = i*256 + t;
            const int row = idx >> 4, cc = idx & 15;
            const float4 v4 = *(const float4*)(V + (b*MSEQ + kn0 + row)*512 + h*64 + cc*4);
            *(float4*)&vt[row][cc*4] = v4;
        }
        if (t < 64) msk[t] = (float)mask[b*MSEQ + kn0 + t];
        __syncthreads();

        // ---- scores -> weights into LDS ----
        float s[16];
        #pragma unroll
        for (int j = 0; j < 16; ++j) s[j] = 0.f;
        #pragma unroll
        for (int d = 0; d < 16; ++d) {
            const float qd = qreg[d];
            #pragma unroll
            for (int u = 0; u < 4; ++u) {
                const float4 kv = *(const float4*)&kT[d][cg*16 + u*4];
                s[u*4+0] = fmaf(qd, kv.x, s[u*4+0]);
                s[u*4+1] = fmaf(qd, kv.y, s[u*4+1]);
                s[u*4+2] = fmaf(qd, kv.z, s[u*4+2]);
                s[u*4+3] = fmaf(qd, kv.w, s[u*4+3]);
            }
        }
        float wsum_t = 0.f;
        #pragma unroll
        for (int j = 0; j < 16; ++j) {
            const float w = msk[cg*16+j] * __expf(fmaxf(0.25f * s[j], 0.f));
            wt[qr][cg*16+j] = w;
            wsum_t += w;
        }
        wsum_t += __shfl_xor(wsum_t, 1, 64);
        wsum_t += __shfl_xor(wsum_t, 2, 64);
        if (cg == 0) wsums[qr] += wsum_t;   // single writer per row; guarded by barriers
        __syncthreads();

        // ---- O += W * V  (4 rows x 4 cols per thread) ----
        #pragma unroll 4
        for (int kc = 0; kc < 16; ++kc) {
            float wv[4][4];
            #pragma unroll
            for (int r = 0; r < 4; ++r)
                *(float4*)&wv[r][0] = *(const float4*)&wt[rg*4+r][kc*4];
            #pragma unroll
            for (int u = 0; u < 4; ++u) {
                const float4 v4 = *(const float4*)&vt[kc*4+u][c4*4];
                #pragma unroll
                for (int r = 0; r < 4; ++r) {
                    acc[r][0] = fmaf(wv[r][u], v4.x, acc[r][0]);
                    acc[r][1] = fmaf(wv[r][u], v4.y, acc[r][1]);
                    acc[r][2] = fmaf(wv[r][u], v4.z, acc[r][2]);
                    acc[r][3] = fmaf(wv[r][u], v4.w, acc[r][3]);
                }
            }
        }
        __syncthreads();
    }

    const float g = gamma[0];
    #pragma unroll
    for (int r = 0; r < 4; ++r) {
        const int row = rg*4 + r;
        const float inv = g / fmaxf(wsums[row], 1e-20f);
        float4 o;
        o.x = acc[r][0]*inv; o.y = acc[r][1]*inv;
        o.z = acc[r][2]*inv; o.w = acc[r][3]*inv;
        *(float4*)(out + (b*MSEQ + m0 + row)*512 + h*64 + c4*4) = o;
    }
}

extern "C" void kernel_launch(void* const* d_in, const int* in_sizes, int n_in,
                              void* d_out, int out_size, void* d_ws, size_t ws_size,
                              hipStream_t stream) {
    const float* x     = (const float*)d_in[0];
    const int*   mask  = (const int*)  d_in[1];
    const float* Wq    = (const float*)d_in[2];
    const float* bq    = (const float*)d_in[3];
    const float* Wk    = (const float*)d_in[4];
    const float* bk    = (const float*)d_in[5];
    const float* Wv    = (const float*)d_in[6];
    const float* bv    = (const float*)d_in[7];
    const float* gamma = (const float*)d_in[8];
    float* outp = (float*)d_out;

    // workspace layout: Q (8192*128 f32) | K (8192*128 f32) | V (8192*512 f32) = 24 MB
    float* Q = (float*)d_ws;
    float* K = Q + 8192*128;
    float* V = K + 8192*128;

    proj_kernel<<<dim3(12, 128), 256, 0, stream>>>(x, Wq, bq, Wk, bk, Wv, bv, Q, K, V);
    attn_kernel<<<dim3(32, 32), 256, 0, stream>>>(Q, K, V, mask, gamma, outp);
}

// Round 2
// 256.283 us; speedup vs baseline: 1.9366x; 1.9366x over previous
//
#include <hip/hip_runtime.h>
#include <hip/hip_bf16.h>

#define MSEQ 2048

typedef __attribute__((ext_vector_type(8))) short short8;
typedef __attribute__((ext_vector_type(4))) float f32x4;

static __device__ __forceinline__ short bf16b(float f) {
    __hip_bfloat16 h = __float2bfloat16(f);   // RNE
    return *reinterpret_cast<short*>(&h);
}

// ---------------- Projection GEMM (fp32 VALU; MFMA port is round 3) ----------------
// [Q|K|V] = x @ [Wq|Wk|Wv] + bias.  Q,K fp32 (8192x128); V emitted as bf16 (8192x512).
__global__ __launch_bounds__(256, 4) void proj_kernel(
    const float* __restrict__ x,
    const float* __restrict__ Wq, const float* __restrict__ bq,
    const float* __restrict__ Wk, const float* __restrict__ bk,
    const float* __restrict__ Wv, const float* __restrict__ bv,
    float* __restrict__ Q, float* __restrict__ K, unsigned short* __restrict__ Vb)
{
    const int nt = blockIdx.x;         // 0..11: 64-col tile across [q|k|v]
    const int r0 = blockIdx.y * 64;

    const float* W; const float* bias; int ld; int n0;
    if (nt < 2)      { W = Wq; bias = bq; ld = 128; n0 = nt * 64; }
    else if (nt < 4) { W = Wk; bias = bk; ld = 128; n0 = (nt - 2) * 64; }
    else             { W = Wv; bias = bv; ld = 512; n0 = (nt - 4) * 64; }

    __shared__ float As[16][72];
    __shared__ float Bs[16][72];

    const int t  = threadIdx.x;
    const int tx = t & 15;
    const int ty = t >> 4;

    float acc[4][4] = {};

    for (int kk = 0; kk < 512; kk += 16) {
        {
            const int row = t >> 2, ch = t & 3;
            const float4 a4 = *(const float4*)(x + (r0 + row) * 512 + kk + ch * 4);
            As[ch*4+0][row] = a4.x; As[ch*4+1][row] = a4.y;
            As[ch*4+2][row] = a4.z; As[ch*4+3][row] = a4.w;
        }
        {
            const int krow = t >> 4, ch = t & 15;
            const float4 b4 = *(const float4*)(W + (kk + krow) * ld + n0 + ch * 4);
            *(float4*)&Bs[krow][ch*4] = b4;
        }
        __syncthreads();
        #pragma unroll
        for (int k = 0; k < 16; ++k) {
            const float4 a4 = *(const float4*)&As[k][ty*4];
            const float4 b4 = *(const float4*)&Bs[k][tx*4];
            const float a[4]  = {a4.x, a4.y, a4.z, a4.w};
            const float bb[4] = {b4.x, b4.y, b4.z, b4.w};
            #pragma unroll
            for (int i = 0; i < 4; ++i)
                #pragma unroll
                for (int j = 0; j < 4; ++j)
                    acc[i][j] = fmaf(a[i], bb[j], acc[i][j]);
        }
        __syncthreads();
    }

    const float4 b4 = *(const float4*)(bias + n0 + tx*4);
    const float bb[4] = {b4.x, b4.y, b4.z, b4.w};
    if (nt < 4) {
        float* out = (nt < 2) ? Q : K;
        #pragma unroll
        for (int i = 0; i < 4; ++i) {
            float4 o;
            o.x = acc[i][0] + bb[0]; o.y = acc[i][1] + bb[1];
            o.z = acc[i][2] + bb[2]; o.w = acc[i][3] + bb[3];
            *(float4*)(out + (r0 + ty*4 + i) * 128 + n0 + tx*4) = o;
        }
    } else {
        #pragma unroll
        for (int i = 0; i < 4; ++i) {
            ushort4 o;
            o.x = (unsigned short)bf16b(acc[i][0] + bb[0]);
            o.y = (unsigned short)bf16b(acc[i][1] + bb[1]);
            o.z = (unsigned short)bf16b(acc[i][2] + bb[2]);
            o.w = (unsigned short)bf16b(acc[i][3] + bb[3]);
            *(ushort4*)(Vb + (size_t)(r0 + ty*4 + i) * 512 + n0 + tx*4) = o;
        }
    }
}

// ---------------- One-off global V transpose: Vb[b*2048+key][512] -> Vt[b*512+ch][2048] ----------------
__global__ __launch_bounds__(256) void vtrans_kernel(
    const unsigned short* __restrict__ Vb, unsigned short* __restrict__ Vt)
{
    const int ct = blockIdx.x;   // 8 ch tiles of 64
    const int kt = blockIdx.y;   // 32 key tiles of 64
    const int b  = blockIdx.z;   // 4
    const int t  = threadIdx.x;
    const int k0 = kt*64, c0 = ct*64;

    __shared__ unsigned short Ts[64*72];   // [ch][key], rows 144B (16B-aligned)

    #pragma unroll
    for (int i = 0; i < 2; ++i) {
        const int idx = i*256 + t;
        const int cg = idx & 7, key = idx >> 3;
        short8 v = *(const short8*)(Vb + ((size_t)(b*MSEQ + k0 + key))*512 + c0 + cg*8);
        #pragma unroll
        for (int u = 0; u < 8; ++u)
            Ts[(cg*8+u)*72 + key] = (unsigned short)v[u];
    }
    __syncthreads();
    #pragma unroll
    for (int i = 0; i < 2; ++i) {
        const int idx = i*256 + t;
        const int kg = idx & 7, ch = idx >> 3;
        short8 v = *(const short8*)&Ts[ch*72 + kg*8];
        *(short8*)(Vt + ((size_t)(b*512 + c0 + ch))*MSEQ + k0 + kg*8) = v;
    }
}

// ---------------- Fused masked attention, bf16 MFMA ----------------
// Per (b,h, 64-q tile): stream 64-key tiles.
// scores: mfma(Q-frag[K=16 zero-padded to 32], K-frag from LDS) -> C-frag
// w = mask ? exp(relu(s/4)) : 0 ; wsum via shfl butterfly (denominator cancellation, see R1)
// W -> LDS (C-layout -> A-layout roundtrip); PV: 8 mfma/wave on 32q x 32ch quadrant.
__global__ __launch_bounds__(256, 4) void attn_mfma(
    const float* __restrict__ Q, const float* __restrict__ K,
    const unsigned short* __restrict__ Vt, const int* __restrict__ mask,
    const float* __restrict__ gamma, float* __restrict__ out)
{
    const int bh = blockIdx.x;       // 32
    const int b  = bh >> 3, h = bh & 7;
    const int m0 = blockIdx.y * 64;  // 32 q-tiles
    const int t  = threadIdx.x;
    const int wave = t >> 6, lane = t & 63, l15 = lane & 15, quad = lane >> 4;

    __shared__ short Ks[64*24];          // [key][24], 48B rows; shorts 16..23 stay 0 (k-padding)
    __shared__ short VtS[64*72];         // [ch][key], 144B rows
    __shared__ short Ws[64*72];          // [q][key],  144B rows
    __shared__ float wsl[64];

    // Q A-fragment (once): dims quad*8..+7 for quad<2, zeros for quads 2/3 (K padding)
    short8 qfrag = {0,0,0,0,0,0,0,0};
    if (quad < 2) {
        const float* qp = Q + (size_t)(b*MSEQ + m0 + wave*16 + l15)*128 + h*16 + quad*8;
        const float4 a = *(const float4*)qp;
        const float4 c = *(const float4*)(qp + 4);
        qfrag[0]=bf16b(a.x); qfrag[1]=bf16b(a.y); qfrag[2]=bf16b(a.z); qfrag[3]=bf16b(a.w);
        qfrag[4]=bf16b(c.x); qfrag[5]=bf16b(c.y); qfrag[6]=bf16b(c.z); qfrag[7]=bf16b(c.w);
    }
    if (t < 64) {   // zero the Ks pad region once (per launch; ws is re-poisoned)
        short8 z = {0,0,0,0,0,0,0,0};
        *(short8*)&Ks[t*24 + 16] = z;
    }

    f32x4 acc[2][2] = {{{0.f,0.f,0.f,0.f},{0.f,0.f,0.f,0.f}},
                       {{0.f,0.f,0.f,0.f},{0.f,0.f,0.f,0.f}}};
    float wsum_acc[4] = {0.f,0.f,0.f,0.f};
    const int qh = wave >> 1, chh = wave & 1;
    const int kso = (quad < 2) ? quad*8 : 16;   // quads 2/3 read the zero pad (broadcast)

    for (int kt = 0; kt < 32; ++kt) {
        const int kn0 = kt*64;
        // ---- stage K tile (fp32 -> bf16) ----
        if (t < 128) {
            const int key = t >> 1, half = t & 1;
            const float* kp = K + (size_t)(b*MSEQ + kn0 + key)*128 + h*16 + half*8;
            const float4 a = *(const float4*)kp;
            const float4 c = *(const float4*)(kp + 4);
            short8 kv;
            kv[0]=bf16b(a.x); kv[1]=bf16b(a.y); kv[2]=bf16b(a.z); kv[3]=bf16b(a.w);
            kv[4]=bf16b(c.x); kv[5]=bf16b(c.y); kv[6]=bf16b(c.z); kv[7]=bf16b(c.w);
            *(short8*)&Ks[key*24 + half*8] = kv;
        }
        // ---- stage Vt tile (bf16 copy, b128 both sides) ----
        #pragma unroll
        for (int i = 0; i < 2; ++i) {
            const int idx = i*256 + t;
            const int kg = idx & 7, ch = idx >> 3;
            short8 v = *(const short8*)(Vt + ((size_t)(b*512 + h*64 + ch))*MSEQ + kn0 + kg*8);
            *(short8*)&VtS[ch*72 + kg*8] = v;
        }
        __syncthreads();

        // ---- scores -> weights (wave = 16-q strip) ----
        float wacc[4] = {0.f,0.f,0.f,0.f};
        #pragma unroll
        for (int c = 0; c < 4; ++c) {
            short8 kfrag = *(const short8*)&Ks[(c*16 + l15)*24 + kso];
            f32x4 s = {0.f,0.f,0.f,0.f};
            s = __builtin_amdgcn_mfma_f32_16x16x32_bf16(qfrag, kfrag, s, 0, 0, 0);
            const int mk = mask[b*MSEQ + kn0 + c*16 + l15];
            #pragma unroll
            for (int r = 0; r < 4; ++r) {
                const float w = mk ? __expf(fmaxf(0.25f*s[r], 0.f)) : 0.f;
                Ws[(wave*16 + quad*4 + r)*72 + c*16 + l15] = bf16b(w);
                wacc[r] += w;
            }
        }
        #pragma unroll
        for (int r = 0; r < 4; ++r) {
            float v = wacc[r];
            v += __shfl_xor(v, 1, 64); v += __shfl_xor(v, 2, 64);
            v += __shfl_xor(v, 4, 64); v += __shfl_xor(v, 8, 64);
            wsum_acc[r] += v;
        }
        __syncthreads();

        // ---- PV: wave quadrant = rows qh*32..+31, chs chh*32..+31 ----
        short8 Af[2][2], Bf[2][2];
        #pragma unroll
        for (int si = 0; si < 2; ++si)
            #pragma unroll
            for (int kh = 0; kh < 2; ++kh)
                Af[si][kh] = *(const short8*)&Ws[((qh*2+si)*16 + l15)*72 + kh*32 + quad*8];
        #pragma unroll
        for (int ci = 0; ci < 2; ++ci)
            #pragma unroll
            for (int kh = 0; kh < 2; ++kh)
                Bf[ci][kh] = *(const short8*)&VtS[((chh*2+ci)*16 + l15)*72 + kh*32 + quad*8];
        #pragma unroll
        for (int si = 0; si < 2; ++si)
            #pragma unroll
            for (int ci = 0; ci < 2; ++ci)
                #pragma unroll
                for (int kh = 0; kh < 2; ++kh)
                    acc[si][ci] = __builtin_amdgcn_mfma_f32_16x16x32_bf16(
                        Af[si][kh], Bf[ci][kh], acc[si][ci], 0, 0, 0);
        __syncthreads();
    }

    if (l15 == 0) {
        #pragma unroll
        for (int r = 0; r < 4; ++r) wsl[wave*16 + quad*4 + r] = wsum_acc[r];
    }
    __syncthreads();

    const float g = gamma[0];
    #pragma unroll
    for (int si = 0; si < 2; ++si) {
        #pragma unroll
        for (int r = 0; r < 4; ++r) {
            const int row = qh*32 + si*16 + quad*4 + r;
            const float inv = g / fmaxf(wsl[row], 1e-20f);
            #pragma unroll
            for (int ci = 0; ci < 2; ++ci) {
                const int col = chh*32 + ci*16 + l15;
                out[(size_t)(b*MSEQ + m0 + row)*512 + h*64 + col] = acc[si][ci][r] * inv;
            }
        }
    }
}

extern "C" void kernel_launch(void* const* d_in, const int* in_sizes, int n_in,
                              void* d_out, int out_size, void* d_ws, size_t ws_size,
                              hipStream_t stream) {
    const float* x     = (const float*)d_in[0];
    const int*   mask  = (const int*)  d_in[1];
    const float* Wq    = (const float*)d_in[2];
    const float* bq    = (const float*)d_in[3];
    const float* Wk    = (const float*)d_in[4];
    const float* bk    = (const float*)d_in[5];
    const float* Wv    = (const float*)d_in[6];
    const float* bv    = (const float*)d_in[7];
    const float* gamma = (const float*)d_in[8];
    float* outp = (float*)d_out;

    // workspace: Q f32 4MB | K f32 4MB | Vb bf16 8MB | Vt bf16 8MB = 24MB (== round-1 usage)
    float* Q = (float*)d_ws;
    float* K = Q + 8192*128;
    unsigned short* Vb = (unsigned short*)(K + 8192*128);
    unsigned short* Vt = Vb + (size_t)8192*512;

    proj_kernel<<<dim3(12, 128), 256, 0, stream>>>(x, Wq, bq, Wk, bk, Wv, bv, Q, K, Vb);
    vtrans_kernel<<<dim3(8, 32, 4), 256, 0, stream>>>(Vb, Vt);
    attn_mfma<<<dim3(32, 32), 256, 0, stream>>>(Q, K, Vt, mask, gamma, outp);
}

// Round 4
// 186.475 us; speedup vs baseline: 2.6615x; 1.3744x over previous
//
#include <hip/hip_runtime.h>
#include <hip/hip_bf16.h>

#define MSEQ 2048

typedef __attribute__((ext_vector_type(8))) short short8;
typedef __attribute__((ext_vector_type(4))) float f32x4;

static __device__ __forceinline__ short bf16b(float f) {
    __hip_bfloat16 h = __float2bfloat16(f);   // RNE
    return *reinterpret_cast<short*>(&h);
}

// async global->LDS, 16B per lane; LDS dest = wave-uniform base + lane*16
static __device__ __forceinline__ void gl_lds16(const void* g, void* l) {
    __builtin_amdgcn_global_load_lds(
        (const __attribute__((address_space(1))) unsigned int*)g,
        (__attribute__((address_space(3))) unsigned int*)l, 16, 0, 0);
}

// ---------------- x fp32 -> bf16 ----------------
__global__ __launch_bounds__(256) void xcvt_kernel(
    const float* __restrict__ x, unsigned short* __restrict__ xb)
{
    const size_t i = ((size_t)blockIdx.x * 256 + threadIdx.x) * 8;
    const float4 a = *(const float4*)(x + i);
    const float4 b = *(const float4*)(x + i + 4);
    short8 o;
    o[0]=bf16b(a.x); o[1]=bf16b(a.y); o[2]=bf16b(a.z); o[3]=bf16b(a.w);
    o[4]=bf16b(b.x); o[5]=bf16b(b.y); o[6]=bf16b(b.z); o[7]=bf16b(b.w);
    *(short8*)(xb + i) = o;
}

// ---------------- W -> WT[n][k] bf16 (n: 0..127 Wq | 128..255 Wk | 256..767 Wv) ----------------
__global__ __launch_bounds__(256) void wtrans_kernel(
    const float* __restrict__ Wq, const float* __restrict__ Wk,
    const float* __restrict__ Wv, unsigned short* __restrict__ WT)
{
    const int nt = blockIdx.x;   // 12 tiles of 64 n
    const int kt = blockIdx.y;   // 8 tiles of 64 k
    const int t  = threadIdx.x;
    const int k0 = kt*64;

    const float* W; int ld, n0;
    if (nt < 2)      { W = Wq; ld = 128; n0 = nt*64; }
    else if (nt < 4) { W = Wk; ld = 128; n0 = (nt-2)*64; }
    else             { W = Wv; ld = 512; n0 = (nt-4)*64; }

    __shared__ unsigned short Ts[64*72];   // [n][k], 144B rows

    #pragma unroll
    for (int s = 0; s < 4; ++s) {
        const int lin = s*256 + t;
        const int krow = lin >> 4, ng = lin & 15;
        const float4 v = *(const float4*)(W + (size_t)(k0+krow)*ld + n0 + ng*4);
        Ts[(ng*4+0)*72 + krow] = (unsigned short)bf16b(v.x);
        Ts[(ng*4+1)*72 + krow] = (unsigned short)bf16b(v.y);
        Ts[(ng*4+2)*72 + krow] = (unsigned short)bf16b(v.z);
        Ts[(ng*4+3)*72 + krow] = (unsigned short)bf16b(v.w);
    }
    __syncthreads();
    #pragma unroll
    for (int s = 0; s < 2; ++s) {
        const int lin = s*256 + t;
        const int nrow = lin >> 3, kg = lin & 7;
        *(short8*)(WT + (size_t)(nt*64 + nrow)*512 + k0 + kg*8) = *(const short8*)&Ts[nrow*72 + kg*8];
    }
}

// ---------------- Fused projection GEMM, bf16 MFMA ----------------
// [Qb|Kb|Vt] = xb @ WT^T + bias. M=8192,N=768,K=512. 128x128 tile, BK=32,
// 4 waves x (4x4 mfma_16x16x32). Epilogue via LDS: Q/K row-major bf16,
// V written TRANSPOSED -> Vt[b*512+ch][key] (kills the separate vtrans pass).
__global__ __launch_bounds__(256, 2) void proj_mfma(
    const unsigned short* __restrict__ xb, const unsigned short* __restrict__ WT,
    const float* __restrict__ bq, const float* __restrict__ bk, const float* __restrict__ bv,
    unsigned short* __restrict__ Qb, unsigned short* __restrict__ Kb, unsigned short* __restrict__ Vt)
{
    const int nt = blockIdx.x;        // 0..5 (0=Q,1=K,2..5=V)
    const int r0 = blockIdx.y * 128;  // m
    const int n0 = nt * 128;
    const int t = threadIdx.x, w = t >> 6, lane = t & 63, l15 = lane & 15, quad = lane >> 4;
    const int qh = w >> 1, chh = w & 1;

    __shared__ short smem[128*136];   // 34816 B; As/Bs alias the front, Ts uses all
    short* As = smem;                 // [128 m][32 k], 64B rows
    short* Bs = smem + 128*32;        // [128 n][32 k]

    f32x4 acc[4][4];
    #pragma unroll
    for (int i = 0; i < 4; ++i)
        #pragma unroll
        for (int j = 0; j < 4; ++j) acc[i][j] = {0.f,0.f,0.f,0.f};

    const int arow = lane >> 2, akg = lane & 3;

    for (int kk = 0; kk < 512; kk += 32) {
        #pragma unroll
        for (int s = 0; s < 2; ++s) {
            const int row = w*32 + s*16 + arow;
            gl_lds16(xb + (size_t)(r0+row)*512 + kk + akg*8, As + (w*32 + s*16)*32);
            gl_lds16(WT + (size_t)(n0+row)*512 + kk + akg*8, Bs + (w*32 + s*16)*32);
        }
        __syncthreads();
        short8 Af[4], Bf[4];
        #pragma unroll
        for (int i = 0; i < 4; ++i) Af[i] = *(const short8*)&As[(qh*64 + i*16 + l15)*32 + quad*8];
        #pragma unroll
        for (int j = 0; j < 4; ++j) Bf[j] = *(const short8*)&Bs[(chh*64 + j*16 + l15)*32 + quad*8];
        #pragma unroll
        for (int i = 0; i < 4; ++i)
            #pragma unroll
            for (int j = 0; j < 4; ++j)
                acc[i][j] = __builtin_amdgcn_mfma_f32_16x16x32_bf16(Af[i], Bf[j], acc[i][j], 0, 0, 0);
        __syncthreads();
    }

    const float* bias = (nt == 0) ? bq : (nt == 1) ? bk : (bv + (nt-2)*128);
    float bj[4];
    #pragma unroll
    for (int j = 0; j < 4; ++j) bj[j] = bias[chh*64 + j*16 + l15];

    short* Ts = smem;   // [128][136]
    if (nt < 2) {       // row-major [m][n]
        #pragma unroll
        for (int i = 0; i < 4; ++i)
            #pragma unroll
            for (int j = 0; j < 4; ++j)
                #pragma unroll
                for (int r = 0; r < 4; ++r)
                    Ts[(qh*64 + i*16 + quad*4 + r)*136 + chh*64 + j*16 + l15] =
                        bf16b(acc[i][j][r] + bj[j]);
    } else {            // transposed [n][m] = [ch][key]
        #pragma unroll
        for (int i = 0; i < 4; ++i)
            #pragma unroll
            for (int j = 0; j < 4; ++j)
                #pragma unroll
                for (int r = 0; r < 4; ++r)
                    Ts[(chh*64 + j*16 + l15)*136 + qh*64 + i*16 + quad*4 + r] =
                        bf16b(acc[i][j][r] + bj[j]);
    }
    __syncthreads();

    if (nt < 2) {
        unsigned short* Out = (nt == 0) ? Qb : Kb;
        #pragma unroll
        for (int s = 0; s < 8; ++s) {
            const int lin = s*256 + t, row = lin >> 4, seg = lin & 15;
            *(short8*)(Out + (size_t)(r0+row)*128 + seg*8) = *(const short8*)&Ts[row*136 + seg*8];
        }
    } else {
        const int b = r0 >> 11, key0 = r0 & 2047, chBase = (nt-2)*128;
        #pragma unroll
        for (int s = 0; s < 8; ++s) {
            const int lin = s*256 + t, row = lin >> 4, seg = lin & 15;
            *(short8*)(Vt + ((size_t)(b*512 + chBase + row))*MSEQ + key0 + seg*8) =
                *(const short8*)&Ts[row*136 + seg*8];
        }
    }
}

// ---------------- Fused masked attention, bf16 MFMA ----------------
__global__ __launch_bounds__(256, 4) void attn_mfma(
    const unsigned short* __restrict__ Qb, const unsigned short* __restrict__ Kb,
    const unsigned short* __restrict__ Vt, const int* __restrict__ mask,
    const float* __restrict__ gamma, float* __restrict__ out)
{
    const int bh = blockIdx.x;       // 32
    const int b  = bh >> 3, h = bh & 7;
    const int m0 = blockIdx.y * 64;  // 32 q-tiles
    const int t  = threadIdx.x;
    const int wave = t >> 6, lane = t & 63, l15 = lane & 15, quad = lane >> 4;

    __shared__ short Ks[64*24];          // [key][24]; shorts 16..23 stay 0 (K=16 padded to 32)
    __shared__ short VtS[64*72];         // [ch][key]
    __shared__ short Ws[64*72];          // [q][key]
    __shared__ float wsl[64];

    short8 qfrag = {0,0,0,0,0,0,0,0};
    if (quad < 2)
        qfrag = *(const short8*)(Qb + (size_t)(b*MSEQ + m0 + wave*16 + l15)*128 + h*16 + quad*8);
    if (t < 64) {
        short8 z = {0,0,0,0,0,0,0,0};
        *(short8*)&Ks[t*24 + 16] = z;
    }

    f32x4 acc[2][2] = {{{0.f,0.f,0.f,0.f},{0.f,0.f,0.f,0.f}},
                       {{0.f,0.f,0.f,0.f},{0.f,0.f,0.f,0.f}}};
    float wsum_acc[4] = {0.f,0.f,0.f,0.f};
    const int qh = wave >> 1, chh = wave & 1;
    const int kso = (quad < 2) ? quad*8 : 16;   // quads 2/3 read the zero pad

    for (int kt = 0; kt < 32; ++kt) {
        const int kn0 = kt*64;
        if (t < 128) {
            const int key = t >> 1, half = t & 1;
            *(short8*)&Ks[key*24 + half*8] =
                *(const short8*)(Kb + (size_t)(b*MSEQ + kn0 + key)*128 + h*16 + half*8);
        }
        #pragma unroll
        for (int i = 0; i < 2; ++i) {
            const int idx = i*256 + t;
            const int kg = idx & 7, ch = idx >> 3;
            *(short8*)&VtS[ch*72 + kg*8] =
                *(const short8*)(Vt + ((size_t)(b*512 + h*64 + ch))*MSEQ + kn0 + kg*8);
        }
        __syncthreads();

        // ---- scores -> weights (wave = 16-q strip) ----
        float wacc[4] = {0.f,0.f,0.f,0.f};
        #pragma unroll
        for (int c = 0; c < 4; ++c) {
            short8 kfrag = *(const short8*)&Ks[(c*16 + l15)*24 + kso];
            f32x4 s = {0.f,0.f,0.f,0.f};
            s = __builtin_amdgcn_mfma_f32_16x16x32_bf16(qfrag, kfrag, s, 0, 0, 0);
            const int mk = mask[b*MSEQ + kn0 + c*16 + l15];
            #pragma unroll
            for (int r = 0; r < 4; ++r) {
                const float w = mk ? __expf(fmaxf(0.25f*s[r], 0.f)) : 0.f;
                Ws[(wave*16 + quad*4 + r)*72 + c*16 + l15] = bf16b(w);
                wacc[r] += w;
            }
        }
        #pragma unroll
        for (int r = 0; r < 4; ++r) {
            float v = wacc[r];
            v += __shfl_xor(v, 1, 64); v += __shfl_xor(v, 2, 64);
            v += __shfl_xor(v, 4, 64); v += __shfl_xor(v, 8, 64);
            wsum_acc[r] += v;
        }
        __syncthreads();

        // ---- PV: wave quadrant = rows qh*32..+31, chs chh*32..+31 ----
        short8 Af[2][2], Bf[2][2];
        #pragma unroll
        for (int si = 0; si < 2; ++si)
            #pragma unroll
            for (int kh = 0; kh < 2; ++kh)
                Af[si][kh] = *(const short8*)&Ws[((qh*2+si)*16 + l15)*72 + kh*32 + quad*8];
        #pragma unroll
        for (int ci = 0; ci < 2; ++ci)
            #pragma unroll
            for (int kh = 0; kh < 2; ++kh)
                Bf[ci][kh] = *(const short8*)&VtS[((chh*2+ci)*16 + l15)*72 + kh*32 + quad*8];
        #pragma unroll
        for (int si = 0; si < 2; ++si)
            #pragma unroll
            for (int ci = 0; ci < 2; ++ci)
                #pragma unroll
                for (int kh = 0; kh < 2; ++kh)
                    acc[si][ci] = __builtin_amdgcn_mfma_f32_16x16x32_bf16(
                        Af[si][kh], Bf[ci][kh], acc[si][ci], 0, 0, 0);
        __syncthreads();
    }

    if (l15 == 0) {
        #pragma unroll
        for (int r = 0; r < 4; ++r) wsl[wave*16 + quad*4 + r] = wsum_acc[r];
    }
    __syncthreads();

    const float g = gamma[0];
    #pragma unroll
    for (int si = 0; si < 2; ++si) {
        #pragma unroll
        for (int r = 0; r < 4; ++r) {
            const int row = qh*32 + si*16 + quad*4 + r;
            const float inv = g / fmaxf(wsl[row], 1e-20f);
            #pragma unroll
            for (int ci = 0; ci < 2; ++ci) {
                const int col = chh*32 + ci*16 + l15;
                out[(size_t)(b*MSEQ + m0 + row)*512 + h*64 + col] = acc[si][ci][r] * inv;
            }
        }
    }
}

extern "C" void kernel_launch(void* const* d_in, const int* in_sizes, int n_in,
                              void* d_out, int out_size, void* d_ws, size_t ws_size,
                              hipStream_t stream) {
    const float* x     = (const float*)d_in[0];
    const int*   mask  = (const int*)  d_in[1];
    const float* Wq    = (const float*)d_in[2];
    const float* bq    = (const float*)d_in[3];
    const float* Wk    = (const float*)d_in[4];
    const float* bk    = (const float*)d_in[5];
    const float* Wv    = (const float*)d_in[6];
    const float* bv    = (const float*)d_in[7];
    const float* gamma = (const float*)d_in[8];
    float* outp = (float*)d_out;

    // ws (bf16 shorts): xb 8MB | WT 0.75MB | Qb 2MB | Kb 2MB | Vt 8MB = 20.75MB
    unsigned short* xb = (unsigned short*)d_ws;
    unsigned short* WT = xb + (size_t)8192*512;
    unsigned short* Qb = WT + (size_t)768*512;
    unsigned short* Kb = Qb + (size_t)8192*128;
    unsigned short* Vt = Kb + (size_t)8192*128;

    xcvt_kernel<<<2048, 256, 0, stream>>>(x, xb);
    wtrans_kernel<<<dim3(12, 8), 256, 0, stream>>>(Wq, Wk, Wv, WT);
    proj_mfma<<<dim3(6, 64), 256, 0, stream>>>(xb, WT, bq, bk, bv, Qb, Kb, Vt);
    attn_mfma<<<dim3(32, 32), 256, 0, stream>>>(Qb, Kb, Vt, mask, gamma, outp);
}

// Round 5
// 169.121 us; speedup vs baseline: 2.9346x; 1.1026x over previous
//
#include <hip/hip_runtime.h>
#include <hip/hip_bf16.h>

#define MSEQ 2048

typedef __attribute__((ext_vector_type(8))) short short8;
typedef __attribute__((ext_vector_type(4))) short short4v;
typedef __attribute__((ext_vector_type(4))) float f32x4;

static __device__ __forceinline__ short bf16b(float f) {
    __hip_bfloat16 h = __float2bfloat16(f);   // RNE
    return *reinterpret_cast<short*>(&h);
}

// async global->LDS, 16B per lane; LDS dest = wave-uniform base + lane*16
static __device__ __forceinline__ void gl_lds16(const void* g, void* l) {
    __builtin_amdgcn_global_load_lds(
        (const __attribute__((address_space(1))) unsigned int*)g,
        (__attribute__((address_space(3))) unsigned int*)l, 16, 0, 0);
}

// ---------------- x fp32 -> bf16 ----------------
__global__ __launch_bounds__(256) void xcvt_kernel(
    const float* __restrict__ x, unsigned short* __restrict__ xb)
{
    const size_t i = ((size_t)blockIdx.x * 256 + threadIdx.x) * 8;
    const float4 a = *(const float4*)(x + i);
    const float4 b = *(const float4*)(x + i + 4);
    short8 o;
    o[0]=bf16b(a.x); o[1]=bf16b(a.y); o[2]=bf16b(a.z); o[3]=bf16b(a.w);
    o[4]=bf16b(b.x); o[5]=bf16b(b.y); o[6]=bf16b(b.z); o[7]=bf16b(b.w);
    *(short8*)(xb + i) = o;
}

// ---------------- W -> WT[n][k] bf16 (n: 0..127 Wq | 128..255 Wk | 256..767 Wv) ----------------
__global__ __launch_bounds__(256) void wtrans_kernel(
    const float* __restrict__ Wq, const float* __restrict__ Wk,
    const float* __restrict__ Wv, unsigned short* __restrict__ WT)
{
    const int nt = blockIdx.x;   // 12 tiles of 64 n
    const int kt = blockIdx.y;   // 8 tiles of 64 k
    const int t  = threadIdx.x;
    const int k0 = kt*64;

    const float* W; int ld, n0;
    if (nt < 2)      { W = Wq; ld = 128; n0 = nt*64; }
    else if (nt < 4) { W = Wk; ld = 128; n0 = (nt-2)*64; }
    else             { W = Wv; ld = 512; n0 = (nt-4)*64; }

    __shared__ unsigned short Ts[64*72];   // [n][k], 144B rows

    #pragma unroll
    for (int s = 0; s < 4; ++s) {
        const int lin = s*256 + t;
        const int krow = lin >> 4, ng = lin & 15;
        const float4 v = *(const float4*)(W + (size_t)(k0+krow)*ld + n0 + ng*4);
        Ts[(ng*4+0)*72 + krow] = (unsigned short)bf16b(v.x);
        Ts[(ng*4+1)*72 + krow] = (unsigned short)bf16b(v.y);
        Ts[(ng*4+2)*72 + krow] = (unsigned short)bf16b(v.z);
        Ts[(ng*4+3)*72 + krow] = (unsigned short)bf16b(v.w);
    }
    __syncthreads();
    #pragma unroll
    for (int s = 0; s < 2; ++s) {
        const int lin = s*256 + t;
        const int nrow = lin >> 3, kg = lin & 7;
        *(short8*)(WT + (size_t)(nt*64 + nrow)*512 + k0 + kg*8) = *(const short8*)&Ts[nrow*72 + kg*8];
    }
}

// ---------------- Fused projection GEMM, bf16 MFMA ----------------
__global__ __launch_bounds__(256, 2) void proj_mfma(
    const unsigned short* __restrict__ xb, const unsigned short* __restrict__ WT,
    const float* __restrict__ bq, const float* __restrict__ bk, const float* __restrict__ bv,
    unsigned short* __restrict__ Qb, unsigned short* __restrict__ Kb, unsigned short* __restrict__ Vt)
{
    const int nt = blockIdx.x;        // 0..5 (0=Q,1=K,2..5=V)
    const int r0 = blockIdx.y * 128;  // m
    const int n0 = nt * 128;
    const int t = threadIdx.x, w = t >> 6, lane = t & 63, l15 = lane & 15, quad = lane >> 4;
    const int qh = w >> 1, chh = w & 1;

    __shared__ short smem[128*136];   // As/Bs alias the front, Ts uses all
    short* As = smem;                 // [128 m][32 k]
    short* Bs = smem + 128*32;        // [128 n][32 k]

    f32x4 acc[4][4];
    #pragma unroll
    for (int i = 0; i < 4; ++i)
        #pragma unroll
        for (int j = 0; j < 4; ++j) acc[i][j] = {0.f,0.f,0.f,0.f};

    const int arow = lane >> 2, akg = lane & 3;

    for (int kk = 0; kk < 512; kk += 32) {
        #pragma unroll
        for (int s = 0; s < 2; ++s) {
            const int row = w*32 + s*16 + arow;
            gl_lds16(xb + (size_t)(r0+row)*512 + kk + akg*8, As + (w*32 + s*16)*32);
            gl_lds16(WT + (size_t)(n0+row)*512 + kk + akg*8, Bs + (w*32 + s*16)*32);
        }
        __syncthreads();
        short8 Af[4], Bf[4];
        #pragma unroll
        for (int i = 0; i < 4; ++i) Af[i] = *(const short8*)&As[(qh*64 + i*16 + l15)*32 + quad*8];
        #pragma unroll
        for (int j = 0; j < 4; ++j) Bf[j] = *(const short8*)&Bs[(chh*64 + j*16 + l15)*32 + quad*8];
        #pragma unroll
        for (int i = 0; i < 4; ++i)
            #pragma unroll
            for (int j = 0; j < 4; ++j)
                acc[i][j] = __builtin_amdgcn_mfma_f32_16x16x32_bf16(Af[i], Bf[j], acc[i][j], 0, 0, 0);
        __syncthreads();
    }

    const float* bias = (nt == 0) ? bq : (nt == 1) ? bk : (bv + (nt-2)*128);
    float bj[4];
    #pragma unroll
    for (int j = 0; j < 4; ++j) bj[j] = bias[chh*64 + j*16 + l15];

    short* Ts = smem;   // [128][136]
    if (nt < 2) {       // row-major [m][n]
        #pragma unroll
        for (int i = 0; i < 4; ++i)
            #pragma unroll
            for (int j = 0; j < 4; ++j)
                #pragma unroll
                for (int r = 0; r < 4; ++r)
                    Ts[(qh*64 + i*16 + quad*4 + r)*136 + chh*64 + j*16 + l15] =
                        bf16b(acc[i][j][r] + bj[j]);
    } else {            // transposed [n][m] = [ch][key]
        #pragma unroll
        for (int i = 0; i < 4; ++i)
            #pragma unroll
            for (int j = 0; j < 4; ++j)
                #pragma unroll
                for (int r = 0; r < 4; ++r)
                    Ts[(chh*64 + j*16 + l15)*136 + qh*64 + i*16 + quad*4 + r] =
                        bf16b(acc[i][j][r] + bj[j]);
    }
    __syncthreads();

    if (nt < 2) {
        unsigned short* Out = (nt == 0) ? Qb : Kb;
        #pragma unroll
        for (int s = 0; s < 8; ++s) {
            const int lin = s*256 + t, row = lin >> 4, seg = lin & 15;
            *(short8*)(Out + (size_t)(r0+row)*128 + seg*8) = *(const short8*)&Ts[row*136 + seg*8];
        }
    } else {
        const int b = r0 >> 11, key0 = r0 & 2047, chBase = (nt-2)*128;
        #pragma unroll
        for (int s = 0; s < 8; ++s) {
            const int lin = s*256 + t, row = lin >> 4, seg = lin & 15;
            *(short8*)(Vt + ((size_t)(b*512 + chBase + row))*MSEQ + key0 + seg*8) =
                *(const short8*)&Ts[row*136 + seg*8];
        }
    }
}

// ---------------- Fused masked attention, bf16 MFMA, S^T score layout ----------------
// Scores: S^T = K.Q^T  (A=K-frag, B=Q-frag) so each lane owns 4 CONSECUTIVE keys
// for one q -> W written as one ds_write_b64 per q-block (was 16 ds_write_b16),
// mask read as one b128 LDS float4 (was 4 global loads), wsum = 2 shuffles/q-block.
__global__ __launch_bounds__(256, 4) void attn_mfma(
    const unsigned short* __restrict__ Qb, const unsigned short* __restrict__ Kb,
    const unsigned short* __restrict__ Vt, const int* __restrict__ mask,
    const float* __restrict__ gamma, float* __restrict__ out)
{
    const int bh = blockIdx.x;       // 32
    const int b  = bh >> 3, h = bh & 7;
    const int m0 = blockIdx.y * 64;  // 32 q-tiles
    const int t  = threadIdx.x;
    const int wave = t >> 6, lane = t & 63, l15 = lane & 15, quad = lane >> 4;

    __shared__ short Ks[64*24];      // [key][24]; shorts 16..23 stay 0 (K=16 padded to 32)
    __shared__ short Qs[64*24];      // [q][24];   same zero-pad trick
    __shared__ short VtS[64*72];     // [ch][key]
    __shared__ short Ws[64*72];      // [q][key]
    __shared__ float msk[64];
    __shared__ float wsl[4*64];      // per-wave wsum partials
    __shared__ float wsums[64];

    // zero the k-pad of Ks and Qs once; stage Q tile once
    if (t < 64) {
        short8 z = {0,0,0,0,0,0,0,0};
        *(short8*)&Ks[t*24 + 16] = z;
        *(short8*)&Qs[t*24 + 16] = z;
    }
    if (t < 128) {
        const int row = t >> 1, half = t & 1;
        *(short8*)&Qs[row*24 + half*8] =
            *(const short8*)(Qb + (size_t)(b*MSEQ + m0 + row)*128 + h*16 + half*8);
    }
    __syncthreads();

    const int kso = (quad < 2) ? quad*8 : 16;   // quads 2/3 read the zero pad (d>=16)
    short8 qfrag[4];
    #pragma unroll
    for (int c = 0; c < 4; ++c)
        qfrag[c] = *(const short8*)&Qs[(c*16 + l15)*24 + kso];

    f32x4 acc[2][2] = {{{0.f,0.f,0.f,0.f},{0.f,0.f,0.f,0.f}},
                       {{0.f,0.f,0.f,0.f},{0.f,0.f,0.f,0.f}}};
    float wsum_acc[4] = {0.f,0.f,0.f,0.f};
    const int qh = wave >> 1, chh = wave & 1;

    for (int kt = 0; kt < 32; ++kt) {
        const int kn0 = kt*64;
        if (t < 128) {
            const int key = t >> 1, half = t & 1;
            *(short8*)&Ks[key*24 + half*8] =
                *(const short8*)(Kb + (size_t)(b*MSEQ + kn0 + key)*128 + h*16 + half*8);
        }
        #pragma unroll
        for (int i = 0; i < 2; ++i) {
            const int idx = i*256 + t;
            const int kg = idx & 7, ch = idx >> 3;
            *(short8*)&VtS[ch*72 + kg*8] =
                *(const short8*)(Vt + ((size_t)(b*512 + h*64 + ch))*MSEQ + kn0 + kg*8);
        }
        if (t < 64) msk[t] = (float)mask[b*MSEQ + kn0 + t];
        __syncthreads();

        // ---- scores S^T: wave covers keys wave*16..+15, all 64 q via c-loop ----
        const short8 kfrag = *(const short8*)&Ks[(wave*16 + l15)*24 + kso];  // A[m=key=l15][k=d]
        const float4 mk4 = *(const float4*)&msk[wave*16 + quad*4];          // keys quad*4..+3
        #pragma unroll
        for (int c = 0; c < 4; ++c) {
            f32x4 s = {0.f,0.f,0.f,0.f};
            s = __builtin_amdgcn_mfma_f32_16x16x32_bf16(kfrag, qfrag[c], s, 0, 0, 0);
            // lane holds q = c*16+l15, keys = wave*16 + quad*4 + r
            float w0 = mk4.x * __expf(fmaxf(0.25f*s[0], 0.f));
            float w1 = mk4.y * __expf(fmaxf(0.25f*s[1], 0.f));
            float w2 = mk4.z * __expf(fmaxf(0.25f*s[2], 0.f));
            float w3 = mk4.w * __expf(fmaxf(0.25f*s[3], 0.f));
            short4v ws4;
            ws4[0]=bf16b(w0); ws4[1]=bf16b(w1); ws4[2]=bf16b(w2); ws4[3]=bf16b(w3);
            *(short4v*)&Ws[(c*16 + l15)*72 + wave*16 + quad*4] = ws4;   // b64 write
            float tsum = (w0 + w1) + (w2 + w3);
            tsum += __shfl_xor(tsum, 16, 64);
            tsum += __shfl_xor(tsum, 32, 64);
            wsum_acc[c] += tsum;
        }
        __syncthreads();

        // ---- PV: wave quadrant = rows qh*32..+31, chs chh*32..+31 ----
        short8 Af[2][2], Bf[2][2];
        #pragma unroll
        for (int si = 0; si < 2; ++si)
            #pragma unroll
            for (int kh = 0; kh < 2; ++kh)
                Af[si][kh] = *(const short8*)&Ws[((qh*2+si)*16 + l15)*72 + kh*32 + quad*8];
        #pragma unroll
        for (int ci = 0; ci < 2; ++ci)
            #pragma unroll
            for (int kh = 0; kh < 2; ++kh)
                Bf[ci][kh] = *(const short8*)&VtS[((chh*2+ci)*16 + l15)*72 + kh*32 + quad*8];
        #pragma unroll
        for (int si = 0; si < 2; ++si)
            #pragma unroll
            for (int ci = 0; ci < 2; ++ci)
                #pragma unroll
                for (int kh = 0; kh < 2; ++kh)
                    acc[si][ci] = __builtin_amdgcn_mfma_f32_16x16x32_bf16(
                        Af[si][kh], Bf[ci][kh], acc[si][ci], 0, 0, 0);
        __syncthreads();
    }

    if (quad == 0) {
        #pragma unroll
        for (int c = 0; c < 4; ++c) wsl[wave*64 + c*16 + l15] = wsum_acc[c];
    }
    __syncthreads();
    if (t < 64) wsums[t] = (wsl[t] + wsl[64+t]) + (wsl[128+t] + wsl[192+t]);
    __syncthreads();

    const float g = gamma[0];
    #pragma unroll
    for (int si = 0; si < 2; ++si) {
        #pragma unroll
        for (int r = 0; r < 4; ++r) {
            const int row = qh*32 + si*16 + quad*4 + r;
            const float inv = g / fmaxf(wsums[row], 1e-20f);
            #pragma unroll
            for (int ci = 0; ci < 2; ++ci) {
                const int col = chh*32 + ci*16 + l15;
                out[(size_t)(b*MSEQ + m0 + row)*512 + h*64 + col] = acc[si][ci][r] * inv;
            }
        }
    }
}

extern "C" void kernel_launch(void* const* d_in, const int* in_sizes, int n_in,
                              void* d_out, int out_size, void* d_ws, size_t ws_size,
                              hipStream_t stream) {
    const float* x     = (const float*)d_in[0];
    const int*   mask  = (const int*)  d_in[1];
    const float* Wq    = (const float*)d_in[2];
    const float* bq    = (const float*)d_in[3];
    const float* Wk    = (const float*)d_in[4];
    const float* bk    = (const float*)d_in[5];
    const float* Wv    = (const float*)d_in[6];
    const float* bv    = (const float*)d_in[7];
    const float* gamma = (const float*)d_in[8];
    float* outp = (float*)d_out;

    // ws (bf16 shorts): xb 8MB | WT 0.75MB | Qb 2MB | Kb 2MB | Vt 8MB
    unsigned short* xb = (unsigned short*)d_ws;
    unsigned short* WT = xb + (size_t)8192*512;
    unsigned short* Qb = WT + (size_t)768*512;
    unsigned short* Kb = Qb + (size_t)8192*128;
    unsigned short* Vt = Kb + (size_t)8192*128;

    xcvt_kernel<<<2048, 256, 0, stream>>>(x, xb);
    wtrans_kernel<<<dim3(12, 8), 256, 0, stream>>>(Wq, Wk, Wv, WT);
    proj_mfma<<<dim3(6, 64), 256, 0, stream>>>(xb, WT, bq, bk, bv, Qb, Kb, Vt);
    attn_mfma<<<dim3(32, 32), 256, 0, stream>>>(Qb, Kb, Vt, mask, gamma, outp);
}